// Round 8
// baseline (4839.599 us; speedup 1.0000x reference)
//
#include <hip/hip_runtime.h>
#include <hip/hip_bf16.h>
#include <math.h>

#define N_NODES 50000
#define M_PAD   50048           // 782 blocks * 64 rows
#define E_EDGES 800000
#define IN_DIM  512
#define HDIM    128
#define CDIM    40
#define LAYERS  8
#define NB      196             // scan blocks: ceil(50000/256)
#define CHUNK   1024            // edge-meta LDS chunk
#define SUPW    132             // sup LDS row stride (fp32), 128+4 pad

typedef __attribute__((ext_vector_type(8))) short short8;
typedef __attribute__((ext_vector_type(4))) short short4v;
typedef __attribute__((ext_vector_type(4))) float floatx4;
typedef unsigned short ushort_t;

__device__ inline float bf2f(unsigned short u) {
    return __uint_as_float(((unsigned)u) << 16);
}
__device__ inline unsigned short f2bf(float v) {
    __hip_bfloat16 b = __float2bfloat16(v);
    return *reinterpret_cast<unsigned short*>(&b);
}

// ---------------- CSR build ----------------

__global__ void hist_kernel(const int* __restrict__ dst, int* __restrict__ cnt) {
    int i = blockIdx.x * blockDim.x + threadIdx.x;
    if (i < E_EDGES) atomicAdd(&cnt[dst[i]], 1);
}

__global__ void scanA(const int* __restrict__ cnt, int* __restrict__ bsum) {
    __shared__ int sm[256];
    int t = threadIdx.x, i = blockIdx.x * 256 + t;
    sm[t] = (i < N_NODES) ? cnt[i] : 0;
    __syncthreads();
    for (int d = 128; d > 0; d >>= 1) {
        if (t < d) sm[t] += sm[t + d];
        __syncthreads();
    }
    if (t == 0) bsum[blockIdx.x] = sm[0];
}

__global__ void scanB(const int* __restrict__ bsum, int* __restrict__ boff) {
    __shared__ int sm[256];
    int t = threadIdx.x;
    sm[t] = (t < NB) ? bsum[t] : 0;
    __syncthreads();
    for (int d = 1; d < 256; d <<= 1) {
        int v = (t >= d) ? sm[t - d] : 0;
        __syncthreads();
        sm[t] += v;
        __syncthreads();
    }
    if (t < NB) boff[t] = (t > 0) ? sm[t - 1] : 0;
}

__global__ void scanC(const int* __restrict__ cnt, const int* __restrict__ boff,
                      int* __restrict__ row_start, int* __restrict__ cursor) {
    __shared__ int sm[256];
    int t = threadIdx.x, i = blockIdx.x * 256 + t;
    int v = (i < N_NODES) ? cnt[i] : 0;
    sm[t] = v;
    __syncthreads();
    for (int d = 1; d < 256; d <<= 1) {
        int x = (t >= d) ? sm[t - d] : 0;
        __syncthreads();
        sm[t] += x;
        __syncthreads();
    }
    if (i < N_NODES) {
        int incl = boff[blockIdx.x] + sm[t];
        int excl = incl - v;
        row_start[i] = excl;
        cursor[i]    = excl;
        if (i == N_NODES - 1) row_start[N_NODES] = incl;
    }
}

__global__ void scatter_kernel(const int* __restrict__ ei, const float* __restrict__ normA,
                               int* __restrict__ cursor, int2* __restrict__ perm) {
    int i = blockIdx.x * blockDim.x + threadIdx.x;
    if (i >= E_EDGES) return;
    int d = ei[E_EDGES + i];
    int idx = atomicAdd(&cursor[d], 1);
    perm[idx] = make_int2(ei[i], __float_as_int(normA[i]));
}

// ------------- weight prep: MFMA-tiled B fragments (coalesced 16B/lane loads) -------------
// Wt0T: [nt 0..7][kc 0..3][ks 0..3][lane 0..63][j 0..7]  (65536 shorts)
//   val = W0[k][n], n = nt*16+(lane&15), k = kc*128+ks*32+(lane>>4)*8+j
// WLT:  [l 0..7][nt 0..7][ks 0..3][lane][j]              (131072 shorts)
// W1T:  [nt 0..2][ks 0..3][lane][j]                      (6144 shorts, n>=40 zero)

__global__ void prep_weights(const float* __restrict__ W0, const float* __restrict__ convW,
                             const float* __restrict__ W1,
                             ushort_t* __restrict__ Wt0, ushort_t* __restrict__ WtL,
                             ushort_t* __restrict__ Wt1) {
    int i = blockIdx.x * blockDim.x + threadIdx.x;
    if (i < 65536) {
        int j = i & 7, lane = (i >> 3) & 63, ks = (i >> 9) & 3, kc = (i >> 11) & 3, nt = i >> 13;
        int n = nt * 16 + (lane & 15);
        int k = kc * 128 + ks * 32 + (lane >> 4) * 8 + j;
        Wt0[i] = f2bf(W0[k * HDIM + n]);
        return;
    }
    i -= 65536;
    if (i < 131072) {
        int j = i & 7, lane = (i >> 3) & 63, ks = (i >> 9) & 3, nt = (i >> 11) & 7, l = i >> 14;
        int n = nt * 16 + (lane & 15);
        int k = ks * 32 + (lane >> 4) * 8 + j;
        WtL[i] = f2bf(convW[l * 16384 + k * HDIM + n]);
        return;
    }
    i -= 131072;
    if (i < 6144) {
        int j = i & 7, lane = (i >> 3) & 63, ks = (i >> 9) & 3, nt = i >> 11;
        int n = nt * 16 + (lane & 15);
        int k = ks * 32 + (lane >> 4) * 8 + j;
        Wt1[i] = (n < CDIM) ? f2bf(W1[k * CDIM + n]) : (ushort_t)0;
    }
}

// ---------------- fc0: x = relu(F @ W0 + b0) -> h0b, xab (row-major bf16) -----

#define AROW 520   // 512 + 8 pad (shorts)

__global__ __launch_bounds__(512)
void fc0_mfma(const float* __restrict__ F, const ushort_t* __restrict__ Wt0,
              const float* __restrict__ b0,
              ushort_t* __restrict__ h0b, ushort_t* __restrict__ xab) {
    __shared__ short sA[64][AROW];   // 66.5 KB
    int t = threadIdx.x;
    int wave = t >> 6, lane = t & 63;
    int quad = lane >> 4, l16 = lane & 15;
    int rg = wave >> 1, cg = wave & 1;
    int row0 = blockIdx.x * 64;

    float4 pf[16];
#pragma unroll
    for (int i = 0; i < 16; i++) {
        int idx = t * 4 + i * 2048;
        int r = row0 + (idx >> 9);
        if (r > N_NODES - 1) r = N_NODES - 1;
        pf[i] = *(const float4*)(F + (size_t)r * IN_DIM + (idx & 511));
    }
    __syncthreads();
#pragma unroll
    for (int i = 0; i < 16; i++) {
        int idx = t * 4 + i * 2048;
        short4v s;
        s[0] = (short)f2bf(pf[i].x); s[1] = (short)f2bf(pf[i].y);
        s[2] = (short)f2bf(pf[i].z); s[3] = (short)f2bf(pf[i].w);
        *(short4v*)&sA[idx >> 9][idx & 511] = s;
    }
    __syncthreads();

    floatx4 acc[4];
#pragma unroll
    for (int nt = 0; nt < 4; nt++) acc[nt] = (floatx4){0.f, 0.f, 0.f, 0.f};

#pragma unroll
    for (int kc = 0; kc < 4; kc++) {
#pragma unroll
        for (int ks = 0; ks < 4; ks++) {
            short8 a = *(const short8*)&sA[rg * 16 + l16][kc * 128 + ks * 32 + quad * 8];
#pragma unroll
            for (int nt = 0; nt < 4; nt++) {
                short8 b = ((const short8*)Wt0)[(size_t)(((cg * 4 + nt) * 16 + kc * 4 + ks) * 64 + lane)];
                acc[nt] = __builtin_amdgcn_mfma_f32_16x16x32_bf16(a, b, acc[nt], 0, 0, 0);
            }
        }
    }
#pragma unroll
    for (int nt = 0; nt < 4; nt++) {
        int col = cg * 64 + nt * 16 + l16;
        float bias = b0[col];
#pragma unroll
        for (int r = 0; r < 4; r++) {
            int row = row0 + rg * 16 + quad * 4 + r;
            float v = acc[nt][r] + bias;
            v = v > 0.f ? v : 0.f;
            ushort_t u = f2bf(v);
            h0b[(size_t)row * HDIM + col] = u;
            xab[(size_t)row * HDIM + col] = u;
        }
    }
}

// -------- fused layer: edge-continuous spmm into LDS sup + mix + GEMM --------
// block = 64 rows, 256 thr / 4 waves / 16 slots of 16 lanes.
// slot s processes a contiguous 1/16 of the block's edge range (pipeline never resets).

__global__ void layer_fused(const int* __restrict__ row_start, const int2* __restrict__ perm,
                            const ushort_t* __restrict__ xb, const ushort_t* __restrict__ h0b,
                            const ushort_t* __restrict__ Wt, ushort_t* __restrict__ X,
                            float beta) {
    __shared__ float sSup[64][SUPW];   // 33.8 KB
    __shared__ int2  sMeta[CHUNK];     // 8 KB
    __shared__ int   sRb[65];
    int t = threadIdx.x;
    int wave = t >> 6, lane = t & 63;
    int slot16 = t >> 4;               // 0..15
    int sl = t & 15;                   // lane-in-slot = column group
    int row0 = blockIdx.x * 64;

    if (t <= 64) {
        int idx = row0 + t;
        if (idx > N_NODES) idx = N_NODES;
        sRb[t] = row_start[idx];
    }
    for (int i = t; i < 64 * SUPW; i += 256) ((float*)sSup)[i] = 0.f;
    __syncthreads();

    int E0 = sRb[0], E1 = sRb[64];

    float acc[8];
#pragma unroll
    for (int c = 0; c < 8; c++) acc[c] = 0.f;
    int cur_row = 0;
    int bnd = sRb[1];
    bool dirty = false;

    for (int base = E0; base < E1; base += CHUNK) {
        int cnt = E1 - base; if (cnt > CHUNK) cnt = CHUNK;
        __syncthreads();   // previous chunk fully consumed
        for (int i = t; i < cnt; i += 256) sMeta[i] = perm[base + i];
        __syncthreads();

        int s0 = base + ((cnt * slot16) >> 4);
        int s1 = base + ((cnt * (slot16 + 1)) >> 4);

        int2 m[4]; short8 v[4];
#pragma unroll
        for (int d = 0; d < 4; d++) {
            int e = s0 + d;
            if (e < s1) {
                m[d] = sMeta[e - base];
                v[d] = *(const short8*)(xb + (size_t)m[d].x * HDIM + sl * 8);
            }
        }
        for (int e = s0; e < s1; e++) {
            int d = (e - s0) & 3;
            while (e >= bnd) {          // row transition (rows nondecreasing)
                if (dirty) {
#pragma unroll
                    for (int c = 0; c < 8; c++) {
                        atomicAdd(&sSup[cur_row][sl * 8 + c], acc[c]);
                        acc[c] = 0.f;
                    }
                    dirty = false;
                }
                cur_row++;
                bnd = sRb[cur_row + 1];
            }
            float w = __int_as_float(m[d].y);
#pragma unroll
            for (int c = 0; c < 8; c++) acc[c] += w * bf2f((ushort_t)v[d][c]);
            dirty = true;
            int en = e + 4;
            if (en < s1) {
                m[d] = sMeta[en - base];
                v[d] = *(const short8*)(xb + (size_t)m[d].x * HDIM + sl * 8);
            }
        }
    }
    if (dirty) {
#pragma unroll
        for (int c = 0; c < 8; c++) atomicAdd(&sSup[cur_row][sl * 8 + c], acc[c]);
    }
    __syncthreads();

    // mix: sup = 0.9*sup + 0.1*h0
    for (int i = t; i < 64 * 64; i += 256) {
        int r = i >> 6, c2 = (i & 63) * 2;
        unsigned h = *(const unsigned*)(h0b + (size_t)(row0 + r) * HDIM + c2);
        sSup[r][c2]     = 0.9f * sSup[r][c2]     + 0.1f * __uint_as_float(h << 16);
        sSup[r][c2 + 1] = 0.9f * sSup[r][c2 + 1] + 0.1f * __uint_as_float(h & 0xFFFF0000u);
    }
    __syncthreads();

    // GEMM phase: x' = relu(beta*(sup@W) + (1-beta)*sup)
    int quad = lane >> 4, l16 = lane & 15;
    short8 afrag[4];
#pragma unroll
    for (int ks = 0; ks < 4; ks++) {
        const float* p = &sSup[wave * 16 + l16][ks * 32 + quad * 8];
        float4 u0 = *(const float4*)p;
        float4 u1 = *(const float4*)(p + 4);
        short8 a;
        a[0] = (short)f2bf(u0.x); a[1] = (short)f2bf(u0.y);
        a[2] = (short)f2bf(u0.z); a[3] = (short)f2bf(u0.w);
        a[4] = (short)f2bf(u1.x); a[5] = (short)f2bf(u1.y);
        a[6] = (short)f2bf(u1.z); a[7] = (short)f2bf(u1.w);
        afrag[ks] = a;
    }

    floatx4 gacc[8];
#pragma unroll
    for (int nt = 0; nt < 8; nt++) {
        floatx4 c = (floatx4){0.f, 0.f, 0.f, 0.f};
#pragma unroll
        for (int ks = 0; ks < 4; ks++) {
            short8 b = ((const short8*)Wt)[(size_t)((nt * 4 + ks) * 64 + lane)];
            c = __builtin_amdgcn_mfma_f32_16x16x32_bf16(afrag[ks], b, c, 0, 0, 0);
        }
        gacc[nt] = c;
    }
    float g = 1.f - beta;
#pragma unroll
    for (int nt = 0; nt < 8; nt++) {
        int col = nt * 16 + l16;
#pragma unroll
        for (int r = 0; r < 4; r++) {
            int lrow = wave * 16 + quad * 4 + r;
            float s = sSup[lrow][col];
            float v = beta * gacc[nt][r] + g * s;
            v = v > 0.f ? v : 0.f;
            X[(size_t)(row0 + lrow) * HDIM + col] = f2bf(v);
        }
    }
}

// ---------------- fc1: out = x @ W1 + b1 (fp32 out), LDS-staged A ----------------

__global__ void fc1_mfma(const ushort_t* __restrict__ X, const ushort_t* __restrict__ Wt1,
                         const float* __restrict__ b1, float* __restrict__ out) {
    __shared__ short sX[64][136];
    int t = threadIdx.x;
    int wave = t >> 6, lane = t & 63;
    int quad = lane >> 4, l16 = lane & 15;
    int row0 = blockIdx.x * 64;

#pragma unroll
    for (int i = 0; i < 4; i++) {
        int idx = t + i * 256;
        int r = idx >> 4, c8 = (idx & 15) * 8;
        *(short8*)&sX[r][c8] = *(const short8*)(X + (size_t)(row0 + r) * HDIM + c8);
    }
    __syncthreads();

    short8 afrag[4];
#pragma unroll
    for (int ks = 0; ks < 4; ks++)
        afrag[ks] = *(const short8*)&sX[wave * 16 + l16][ks * 32 + quad * 8];

    floatx4 acc[3];
#pragma unroll
    for (int nt = 0; nt < 3; nt++) {
        floatx4 c = (floatx4){0.f, 0.f, 0.f, 0.f};
#pragma unroll
        for (int ks = 0; ks < 4; ks++) {
            short8 b = ((const short8*)Wt1)[(size_t)((nt * 4 + ks) * 64 + lane)];
            c = __builtin_amdgcn_mfma_f32_16x16x32_bf16(afrag[ks], b, c, 0, 0, 0);
        }
        acc[nt] = c;
    }
#pragma unroll
    for (int nt = 0; nt < 3; nt++) {
        int col = nt * 16 + l16;
        if (col < CDIM) {
            float bias = b1[col];
#pragma unroll
            for (int r = 0; r < 4; r++) {
                int row = row0 + wave * 16 + quad * 4 + r;
                if (row < N_NODES)
                    out[(size_t)row * CDIM + col] = acc[nt][r] + bias;
            }
        }
    }
}

// ---------------- launch ----------------

extern "C" void kernel_launch(void* const* d_in, const int* in_sizes, int n_in,
                              void* d_out, int out_size, void* d_ws, size_t ws_size,
                              hipStream_t stream) {
    const float* F     = (const float*)d_in[0];
    const int*   ei    = (const int*)d_in[1];
    const float* normA = (const float*)d_in[2];
    const float* W0    = (const float*)d_in[3];
    const float* b0    = (const float*)d_in[4];
    const float* convW = (const float*)d_in[5];
    const float* W1    = (const float*)d_in[6];
    const float* b1    = (const float*)d_in[7];
    float*       out   = (float*)d_out;

    // workspace layout (bf16 trunk, row-major), 16B-aligned
    ushort_t* h0b  = (ushort_t*)d_ws;                     // M_PAD*128
    ushort_t* xab  = h0b + (size_t)M_PAD * HDIM;
    ushort_t* xbb  = xab + (size_t)M_PAD * HDIM;
    ushort_t* Wt0  = xbb + (size_t)M_PAD * HDIM;          // 65536
    ushort_t* WtL  = Wt0 + 65536;                         // 131072
    ushort_t* Wt1  = WtL + 131072;                        // 6144
    int*   row_start = (int*)(Wt1 + 6144);
    int*   cursor    = row_start + (N_NODES + 8);
    int*   cnt       = cursor + (N_NODES + 8);
    int*   bsum      = cnt + (N_NODES + 8);
    int*   boff      = bsum + 256;
    int2*  perm      = (int2*)(boff + 256);               // 8B-aligned

    // CSR build
    hipMemsetAsync(cnt, 0, N_NODES * sizeof(int), stream);
    hist_kernel<<<(E_EDGES + 255) / 256, 256, 0, stream>>>(ei + E_EDGES, cnt);
    scanA<<<NB, 256, 0, stream>>>(cnt, bsum);
    scanB<<<1, 256, 0, stream>>>(bsum, boff);
    scanC<<<NB, 256, 0, stream>>>(cnt, boff, row_start, cursor);
    scatter_kernel<<<(E_EDGES + 255) / 256, 256, 0, stream>>>(ei, normA, cursor, perm);
    prep_weights<<<(65536 + 131072 + 6144 + 255) / 256, 256, 0, stream>>>(
        W0, convW, W1, Wt0, WtL, Wt1);

    fc0_mfma<<<M_PAD / 64, 512, 0, stream>>>(F, Wt0, b0, h0b, xab);

    ushort_t* ping = xab;
    ushort_t* pong = xbb;
    for (int i = 0; i < LAYERS; i++) {
        float beta = logf(0.5f / (float)(i + 1) + 1.0f);
        layer_fused<<<M_PAD / 64, 256, 0, stream>>>(
            row_start, perm, ping, h0b, WtL + (size_t)i * 16384, pong, beta);
        ushort_t* tmp = ping; ping = pong; pong = tmp;
    }
    // after 8 layers (even count), result is back in xab
    fc1_mfma<<<M_PAD / 64, 256, 0, stream>>>(xab, Wt1, b1, out);
}